// Round 10
// baseline (436.135 us; speedup 1.0000x reference)
//
#include <hip/hip_runtime.h>

// Problem constants
#define CI    16
#define CO    16
#define HID   256
#define IMGH  128
#define IMGW  128
#define RSTR  132            // shPatch row stride in shorts
#define RLEN  130            // 128 + 2 halo
#define MAXEVT 512

typedef float f32x2 __attribute__((ext_vector_type(2)));

__device__ __host__ __forceinline__ short f2bf(float f) {
  union { float f; unsigned u; } c; c.f = f;
  unsigned b = c.u + 0x7FFFu + ((c.u >> 16) & 1u);   // RNE
  return (short)(b >> 16);
}
__device__ __forceinline__ float blo(unsigned u){ return __uint_as_float(u << 16); }
__device__ __forceinline__ float bhi(unsigned u){ return __uint_as_float(u & 0xFFFF0000u); }
__device__ __forceinline__ float bfu(short s){ return __uint_as_float(((unsigned)(unsigned short)s) << 16); }

// ---------------------------------------------------------------------------
// Prep: W2 [256][2304] fp32 -> W2s SoA dwords [k][dw:5][t:256].
// Thread t owns cols 9t..9t+8 (col = o*144 + ci*9 + q); dword dw of thread t
// packs bf16 cols (2dw, 2dw+1), dw=4 packs (col8, 0). Event-row load in the
// main kernel = 5 perfectly-coalesced 256B global_load_dword per event.
// ---------------------------------------------------------------------------
__global__ void prep_w2s(const float* __restrict__ W2, unsigned* __restrict__ W2s) {
  const int k = blockIdx.x;          // 0..255
  const int t = threadIdx.x;         // 0..255
  const float* src = W2 + k * (CO * 144) + t * 9;
  #pragma unroll
  for (int dw = 0; dw < 5; ++dw) {
    unsigned lo = (unsigned)(unsigned short)f2bf(src[2 * dw]);
    unsigned hi = (dw < 4) ? (unsigned)(unsigned short)f2bf(src[2 * dw + 1]) : 0u;
    W2s[(k * 5 + dw) * 256 + t] = lo | (hi << 16);
  }
}

// ---------------------------------------------------------------------------
// v21 = v19's breakpoint-sweep skeleton (VGPR 44, no spill) + the latency
// chains removed WITHOUT v20's register bloat (v20: sg[27]+ends[16]+pv[16]+
// P[16] -> 128 VGPR + 860MB scratch traffic; lesson: add ONLY pv[16]).
//  (1) pv[16] + ONE in-place butterfly per 16 px (15 shfl, depth 4) replaces
//      the per-pixel 4-level reduce (25k -> 1.6k cyc/wave).
//  (2) SoA W2s: 5 coalesced dword loads per event (was 5 segmented gathers).
//  (3) Event pipeline deepened to 2-iteration cover: rows u(cur)/v(next)/
//      t(issued now, used in 2 iters), meta 3-deep; named regs, rotate-by-copy.
//  (4) tid-0 serial 128-elem prefix scan (~15k cyc) -> wave-0 shfl_up scan.
// Thread t = (o=t>>4, ci=t&15) owns cols 9t..9t+8; S=(S0,S1) f32x2 S[9];
// h_k(x)=relu(ka*(x-th)) -> kern(x,:) = S0 + dx*S1 piecewise-linear, events
// at breakpoint crossings. grid = 4*128 = 512 blocks x 256 thr; no MFMA.
// ---------------------------------------------------------------------------
__global__ __launch_bounds__(256, 2)
void ngconv_sweep(const float* __restrict__ in, const float* __restrict__ foa,
                  const float* __restrict__ W1, const float* __restrict__ b1,
                  const unsigned* __restrict__ W2s, const float* __restrict__ b2,
                  float* __restrict__ out) {
  __shared__ short shPatch[48 * RSTR];     // reflect-extended rows, 12.4 KB
  __shared__ float shO[CO * 129];          // output staging, 8.3 KB
  __shared__ unsigned evOff[MAXEVT];       // W2s dword offset per event
  __shared__ float evC[MAXEVT];            // signed c coef
  __shared__ float evA[MAXEVT];            // signed a coef
  __shared__ int bstart[IMGW + 1];         // bucket prefix
  __shared__ int cnt[IMGW];                // histogram / cursors
  __shared__ int nentSh;

  const int tid  = threadIdx.x;
  const int o    = tid >> 4;        // output channel
  const int ic   = tid & 15;        // input channel
  const int c15  = tid & 15;

  const int blk = blockIdx.x;
  const int b = blk >> 7;
  const int y = blk & 127;

  const float fx = foa[b * 2 + 0];
  const float fy = foa[b * 2 + 1];
  const float dyv = (float)y - fy;
  const int ry0 = (y == 0) ? 1 : (y - 1);
  const int ry2 = (y == IMGH - 1) ? (IMGH - 2) : (y + 1);

  // ---- patch rows (v14/v19's verified setup)
  for (int e = tid; e < 48 * RLEN; e += 256) {
    int r = e / RLEN, xx = e - r * RLEN;
    int i2 = r / 3, dyr = r - i2 * 3;
    int ryr = (dyr == 0) ? ry0 : ((dyr == 1) ? y : ry2);
    int x = xx - 1;
    x = (x < 0) ? 1 : ((x > IMGW - 1) ? (IMGW - 2) : x);   // reflect
    shPatch[r * RSTR + xx] = f2bf(in[((b * CI + i2) * IMGH + ryr) * IMGW + x]);
  }

  for (int e = tid; e < IMGW; e += 256) cnt[e] = 0;
  __syncthreads();

  // ---- bucketing: thread tid handles k = tid (v19 logic, verified;
  // CONSISTENCY: act0 and crossing derived from the SAME th comparison)
  float ka = W1[tid];                         // W1[0][k]
  float kc = fmaf(dyv, W1[HID + tid], b1[tid]);
  bool act0 = false;
  int xe = -1;
  if (ka != 0.f) {
    float th = fx - kc / ka;                  // breakpoint in x
    if (ka > 0.f) {
      act0 = (th < 0.f);
      if (th >= 0.f && th < 127.f) xe = (int)floorf(th) + 1;
    } else {
      act0 = (th > 0.f);
      if (th > 0.f && th < 127.f) xe = (int)floorf(th) + 1;
    }
  } else {
    act0 = (kc > 0.f);
  }
  if (act0)   atomicAdd(&cnt[0], 1);
  if (xe > 0) atomicAdd(&cnt[xe], 1);
  __syncthreads();

  // ---- wave-0 prefix scan of cnt[128] (2 elems/lane + shfl_up inclusive)
  if (tid < 64) {
    int c0 = cnt[2 * tid], c1 = cnt[2 * tid + 1];
    int s = c0 + c1;
    int inc = s;
    #pragma unroll
    for (int d = 1; d <= 32; d <<= 1) {
      int r = __shfl_up(inc, d, 64);
      if (tid >= d) inc += r;
    }
    int exc = inc - s;
    bstart[2 * tid] = exc;
    bstart[2 * tid + 1] = exc + c0;
    if (tid == 63) { bstart[IMGW] = inc; nentSh = inc; }
  }
  __syncthreads();
  for (int e = tid; e < IMGW; e += 256) cnt[e] = bstart[e];   // cursors
  __syncthreads();
  if (act0) {
    int p = atomicAdd(&cnt[0], 1);
    evOff[p] = (unsigned)tid * 1280u;         // dword offset: k*5*256
    evC[p] = kc; evA[p] = ka;
  }
  if (xe > 0) {
    int p = atomicAdd(&cnt[xe], 1);
    float sg = (ka > 0.f) ? 1.f : -1.f;       // activate vs deactivate
    evOff[p] = (unsigned)tid * 1280u;
    evC[p] = sg * kc; evA[p] = sg * ka;
  }

  // ---- S init: S0 = b2, S1 = 0
  f32x2 S[9];
  {
    const float* bp = b2 + tid * 9;
    #pragma unroll
    for (int q = 0; q < 9; ++q) S[q] = (f32x2){bp[q], 0.f};
  }
  __syncthreads();
  const int nent = nentSh;

  // ---- event pipeline prime (rows for 0,1 issued; meta for 0,1,2)
  unsigned u0=0,u1=0,u2=0,u3=0,u4=0;  float cc=0.f, ca=0.f;   // event aptr
  unsigned v0=0,v1=0,v2=0,v3=0,v4=0;  float nc=0.f, na=0.f;   // event aptr+1
  unsigned wOff=0; float wc=0.f, wa=0.f;                      // meta aptr+2
  if (nent > 0) {
    unsigned off = evOff[0]; cc = evC[0]; ca = evA[0];
    const unsigned* gp = W2s + off;
    u0 = gp[tid]; u1 = gp[256 + tid]; u2 = gp[512 + tid];
    u3 = gp[768 + tid]; u4 = gp[1024 + tid];
  }
  if (nent > 1) {
    unsigned off = evOff[1]; nc = evC[1]; na = evA[1];
    const unsigned* gp = W2s + off;
    v0 = gp[tid]; v1 = gp[256 + tid]; v2 = gp[512 + tid];
    v3 = gp[768 + tid]; v4 = gp[1024 + tid];
  }
  if (nent > 2) { wOff = evOff[2]; wc = evC[2]; wa = evA[2]; }

  // ---- sliding 3x3 patch window (this thread's channel ic)
  const short* pr0 = &shPatch[(ic * 3 + 0) * RSTR];
  const short* pr1 = &shPatch[(ic * 3 + 1) * RSTR];
  const short* pr2 = &shPatch[(ic * 3 + 2) * RSTR];
  float w00 = bfu(pr0[0]), w01 = bfu(pr0[1]);
  float w10 = bfu(pr1[0]), w11 = bfu(pr1[1]);
  float w20 = bfu(pr2[0]), w21 = bfu(pr2[1]);
  float f0 = bfu(pr0[2]), f1 = bfu(pr1[2]), f2 = bfu(pr2[2]);

  int aptr = 0;
  int endCur = bstart[1];

  #pragma unroll 1
  for (int xb = 0; xb < IMGW; xb += 16) {
    float pv[16];
    #pragma unroll
    for (int j = 0; j < 16; ++j) {
      const int x = xb + j;
      // prefetch next patch col + next bucket end
      float g0 = 0.f, g1 = 0.f, g2 = 0.f;
      if (x + 3 < RLEN) { g0 = bfu(pr0[x+3]); g1 = bfu(pr1[x+3]); g2 = bfu(pr2[x+3]); }
      int endNxt = (x + 2 <= IMGW) ? bstart[x + 2] : 0;

      // apply this pixel's events (block-uniform control flow)
      while (aptr < endCur) {
        // issue rows for aptr+2 (consumed 2 iterations from now)
        unsigned t0=0,t1=0,t2=0,t3=0,t4=0;
        if (aptr + 2 < nent) {
          const unsigned* gp = W2s + wOff;
          t0 = gp[tid]; t1 = gp[256 + tid]; t2 = gp[512 + tid];
          t3 = gp[768 + tid]; t4 = gp[1024 + tid];
        }
        // read meta for aptr+3
        unsigned xOff = 0; float xc = 0.f, xa = 0.f;
        if (aptr + 3 < nent) { xOff = evOff[aptr+3]; xc = evC[aptr+3]; xa = evA[aptr+3]; }
        // apply current event
        f32x2 ca2 = (f32x2){cc, ca};
        S[0] += (f32x2){blo(u0), blo(u0)} * ca2;
        S[1] += (f32x2){bhi(u0), bhi(u0)} * ca2;
        S[2] += (f32x2){blo(u1), blo(u1)} * ca2;
        S[3] += (f32x2){bhi(u1), bhi(u1)} * ca2;
        S[4] += (f32x2){blo(u2), blo(u2)} * ca2;
        S[5] += (f32x2){bhi(u2), bhi(u2)} * ca2;
        S[6] += (f32x2){blo(u3), blo(u3)} * ca2;
        S[7] += (f32x2){bhi(u3), bhi(u3)} * ca2;
        S[8] += (f32x2){blo(u4), blo(u4)} * ca2;
        // rotate (register renaming, no dynamic indexing)
        u0=v0; u1=v1; u2=v2; u3=v3; u4=v4; cc=nc; ca=na;
        v0=t0; v1=t1; v2=t2; v3=t3; v4=t4; nc=wc; na=wa;
        wOff=xOff; wc=xc; wa=xa;
        ++aptr;
      }

      // contraction: out(o,x) contribution = sum_q patch(ic,q,x)*S[q]
      float w02 = f0, w12 = f1, w22 = f2;
      f32x2 p = (f32x2){0.f, 0.f};
      p += (f32x2){w00, w00} * S[0];
      p += (f32x2){w01, w01} * S[1];
      p += (f32x2){w02, w02} * S[2];
      p += (f32x2){w10, w10} * S[3];
      p += (f32x2){w11, w11} * S[4];
      p += (f32x2){w12, w12} * S[5];
      p += (f32x2){w20, w20} * S[6];
      p += (f32x2){w21, w21} * S[7];
      p += (f32x2){w22, w22} * S[8];
      pv[j] = fmaf((float)x - fx, p[1], p[0]);   // dx lane-uniform per px

      w00 = w01; w01 = w02; w10 = w11; w11 = w12; w20 = w21; w21 = w22;
      f0 = g0; f1 = g1; f2 = g2;
      endCur = endNxt;
    }

    // ---- ONE reduce-scatter butterfly for 16 px (in-place on pv):
    // final pv[0] at lane c15 = sum over the 16 ic-lanes for px xb+c15
    #pragma unroll
    for (int m = 8; m >= 1; m >>= 1) {
      const bool hi = (c15 & m) != 0;
      #pragma unroll
      for (int j2 = 0; j2 < m; ++j2) {
        float keep = hi ? pv[j2 + m] : pv[j2];
        float send = hi ? pv[j2] : pv[j2 + m];
        float recv = __shfl_xor(send, m, 64);
        pv[j2] = keep + recv;
      }
    }
    shO[o * 129 + xb + c15] = pv[0];
  }

  // ---- coalesced flush (full 512 B rows)
  __syncthreads();
  #pragma unroll
  for (int u = 0; u < 2; ++u) {
    int f = u * 256 + tid;
    int row = f >> 5, c4 = f & 31;
    float4 v;
    v.x = shO[row * 129 + c4 * 4 + 0];
    v.y = shO[row * 129 + c4 * 4 + 1];
    v.z = shO[row * 129 + c4 * 4 + 2];
    v.w = shO[row * 129 + c4 * 4 + 3];
    *(float4*)&out[((b * CO + row) * IMGH + y) * IMGW + c4 * 4] = v;
  }
}

// ---------------------------------------------------------------------------
extern "C" void kernel_launch(void* const* d_in, const int* in_sizes, int n_in,
                              void* d_out, int out_size, void* d_ws, size_t ws_size,
                              hipStream_t stream) {
  const float* in  = (const float*)d_in[0];   // [4,16,128,128]
  const float* foa = (const float*)d_in[1];   // [4,2]
  const float* W1  = (const float*)d_in[2];   // [2,256]
  const float* b1  = (const float*)d_in[3];   // [256]
  const float* W2  = (const float*)d_in[4];   // [256,2304]
  const float* b2  = (const float*)d_in[5];   // [2304]
  float* out = (float*)d_out;
  unsigned* W2s = (unsigned*)d_ws;            // 256*5*256 dwords = 1.31 MB

  prep_w2s<<<256, 256, 0, stream>>>(W2, W2s);
  ngconv_sweep<<<512, 256, 0, stream>>>(in, foa, W1, b1, W2s, b2, out);
}

// Round 11
// 361.301 us; speedup vs baseline: 1.2071x; 1.2071x over previous
//
#include <hip/hip_runtime.h>

// Problem constants
#define CI    16
#define CO    16
#define HID   256
#define IMGH  128
#define IMGW  128
#define XW    64             // px per block (x-split halves a row)
#define RSTR  68             // shPatch row stride in shorts (136 B)
#define RLEN  66             // 64 px + 2 halo
#define MAXEVT 512

typedef float f32x2 __attribute__((ext_vector_type(2)));

__device__ __host__ __forceinline__ short f2bf(float f) {
  union { float f; unsigned u; } c; c.f = f;
  unsigned b = c.u + 0x7FFFu + ((c.u >> 16) & 1u);   // RNE
  return (short)(b >> 16);
}
__device__ __forceinline__ float blo(unsigned u){ return __uint_as_float(u << 16); }
__device__ __forceinline__ float bhi(unsigned u){ return __uint_as_float(u & 0xFFFF0000u); }
__device__ __forceinline__ float bfu(short s){ return __uint_as_float(((unsigned)(unsigned short)s) << 16); }

// ---------------------------------------------------------------------------
// Prep: W2 [256][2304] fp32 -> W2s SoA dwords [k][dw:5][t:256].
// Thread t owns cols 9t..9t+8 (col = o*144 + ci*9 + q); dword dw of thread t
// packs bf16 cols (2dw, 2dw+1); dw=4 packs (col8, 0). Event-row load in the
// main kernel = 5 perfectly-coalesced dword loads per event. (verified v21)
// ---------------------------------------------------------------------------
__global__ void prep_w2s(const float* __restrict__ W2, unsigned* __restrict__ W2s) {
  const int k = blockIdx.x;          // 0..255
  const int t = threadIdx.x;         // 0..255
  const float* src = W2 + k * (CO * 144) + t * 9;
  #pragma unroll
  for (int dw = 0; dw < 5; ++dw) {
    unsigned lo = (unsigned)(unsigned short)f2bf(src[2 * dw]);
    unsigned hi = (dw < 4) ? (unsigned)(unsigned short)f2bf(src[2 * dw + 1]) : 0u;
    W2s[(k * 5 + dw) * 256 + t] = lo | (hi << 16);
  }
}

// ---------------------------------------------------------------------------
// v22 = v19's breakpoint-sweep skeleton (44 VGPR, no spill) repackaged for
// latency hiding WITHOUT v20/v21's register bloat (both spilled at 128 VGPR
// from 16x-unrolled bodies + deep pipelines; FETCH/WRITE blew to 0.4-1 GB).
//  (1) x-split: grid 1024, 64 px/block -> 4 blocks/CU = 4 waves/SIMD (2x TLP
//      for the latency-bound event bursts); LDS ~17 KB; bucket conds shift x0.
//  (2) pv[8] + ONE 8-value butterfly per 8 px (8 shfl vs v19's 64; depth 4
//      once per batch). Only +8 regs; 8x-unrolled body (half of v21's 16).
//  (3) wave-0 shfl_up prefix scan (kills v19's ~20k-cyc tid-0 serial scan).
//  (4) SoA W2s event loads, v19's original 2-deep pipeline (named regs).
// Thread t = (o=t>>4, ci=t&15) owns cols 9t..9t+8; S=(S0,S1) f32x2 S[9];
// h_k(x)=relu(ka*dx+kc) piecewise-linear in x -> kern = S0 + dx*S1 with
// rank-1 updates at breakpoint crossings. CONSISTENCY: act-at-x0 and the
// crossing event derive from the SAME th comparison.
// grid = 4b * 128y * 2half = 1024 blocks x 256 threads; no MFMA.
// ---------------------------------------------------------------------------
__global__ __launch_bounds__(256, 4)
void ngconv_sweep(const float* __restrict__ in, const float* __restrict__ foa,
                  const float* __restrict__ W1, const float* __restrict__ b1,
                  const unsigned* __restrict__ W2s, const float* __restrict__ b2,
                  float* __restrict__ out) {
  __shared__ short shPatch[48 * RSTR];     // reflect-extended rows, 6.5 KB
  __shared__ float shO[CO * XW];           // output staging, 4 KB
  __shared__ unsigned evOff[MAXEVT];       // W2s dword offset per event
  __shared__ float evC[MAXEVT];            // signed c coef
  __shared__ float evA[MAXEVT];            // signed a coef
  __shared__ int bstart[XW + 1];           // bucket prefix
  __shared__ int cnt[XW];                  // histogram / cursors
  __shared__ int nentSh;

  const int tid  = threadIdx.x;
  const int o    = tid >> 4;        // output channel
  const int ic   = tid & 15;        // input channel
  const int c15  = tid & 15;

  const int blk = blockIdx.x;
  const int b   = blk >> 8;
  const int rem = blk & 255;
  const int y   = rem >> 1;
  const int x0  = (rem & 1) << 6;

  const float fx = foa[b * 2 + 0];
  const float fy = foa[b * 2 + 1];
  const float dyv = (float)y - fy;
  const int ry0 = (y == 0) ? 1 : (y - 1);
  const int ry2 = (y == IMGH - 1) ? (IMGH - 2) : (y + 1);

  // ---- patch rows (v12/v13's verified 64-px setup)
  for (int e = tid; e < 48 * RLEN; e += 256) {
    int r = e / RLEN, xx = e - r * RLEN;
    int i2 = r / 3, dyr = r - i2 * 3;
    int ryr = (dyr == 0) ? ry0 : ((dyr == 1) ? y : ry2);
    int x = x0 + xx - 1;
    x = (x < 0) ? 1 : ((x > IMGW - 1) ? (IMGW - 2) : x);   // reflect
    shPatch[r * RSTR + xx] = f2bf(in[((b * CI + i2) * IMGH + ryr) * IMGW + x]);
  }

  if (tid < XW) cnt[tid] = 0;
  __syncthreads();

  // ---- bucketing: thread tid handles k = tid (v19 logic shifted by x0)
  float ka = W1[tid];                         // W1[0][k]
  float kc = fmaf(dyv, W1[HID + tid], b1[tid]);
  bool act0 = false;
  int xe = -1;
  const float x0f = (float)x0;
  if (ka != 0.f) {
    float th = fx - kc / ka;                  // breakpoint in image-x
    if (ka > 0.f) {                           // active for x > th
      act0 = (th < x0f);
      if (th >= x0f && th < x0f + 63.f) xe = (int)floorf(th) + 1 - x0;
    } else {                                  // active for x < th
      act0 = (th > x0f);
      if (th > x0f && th < x0f + 63.f) xe = (int)floorf(th) + 1 - x0;
    }
  } else {
    act0 = (kc > 0.f);
  }
  if (act0)   atomicAdd(&cnt[0], 1);
  if (xe > 0) atomicAdd(&cnt[xe], 1);
  __syncthreads();

  // ---- wave-0 shfl_up inclusive scan over 64 buckets
  if (tid < 64) {
    int c = cnt[tid];
    int inc = c;
    #pragma unroll
    for (int d = 1; d <= 32; d <<= 1) {
      int r = __shfl_up(inc, d, 64);
      if (tid >= d) inc += r;
    }
    bstart[tid] = inc - c;                    // exclusive
    if (tid == 63) { bstart[XW] = inc; nentSh = inc; }
  }
  __syncthreads();
  if (tid < XW) cnt[tid] = bstart[tid];       // cursors
  __syncthreads();
  if (act0) {
    int p = atomicAdd(&cnt[0], 1);
    evOff[p] = (unsigned)tid * 1280u;         // dword offset: k*5*256
    evC[p] = kc; evA[p] = ka;
  }
  if (xe > 0) {
    int p = atomicAdd(&cnt[xe], 1);
    float sg = (ka > 0.f) ? 1.f : -1.f;       // activate vs deactivate
    evOff[p] = (unsigned)tid * 1280u;
    evC[p] = sg * kc; evA[p] = sg * ka;
  }

  // ---- S init: S0 = b2, S1 = 0
  f32x2 S[9];
  {
    const float* bp = b2 + tid * 9;
    #pragma unroll
    for (int q = 0; q < 9; ++q) S[q] = (f32x2){bp[q], 0.f};
  }
  __syncthreads();
  const int nent = nentSh;

  // ---- event pipeline prime (v19's 2-deep: rows for 0; meta for 1)
  unsigned r0=0, r1=0, r2=0, r3=0, r4=0;      // rows of event aptr
  float cc=0.f, ca=0.f;                       // coefs of event aptr
  unsigned nOff=0; float nc=0.f, na=0.f;      // meta of event aptr+1
  if (nent > 0) {
    unsigned off = evOff[0]; cc = evC[0]; ca = evA[0];
    const unsigned* gp = W2s + off;
    r0 = gp[tid]; r1 = gp[256 + tid]; r2 = gp[512 + tid];
    r3 = gp[768 + tid]; r4 = gp[1024 + tid];
  }
  if (nent > 1) { nOff = evOff[1]; nc = evC[1]; na = evA[1]; }

  // ---- sliding 3x3 patch window (this thread's channel ic)
  const short* pr0 = &shPatch[(ic * 3 + 0) * RSTR];
  const short* pr1 = &shPatch[(ic * 3 + 1) * RSTR];
  const short* pr2 = &shPatch[(ic * 3 + 2) * RSTR];
  float w00 = bfu(pr0[0]), w01 = bfu(pr0[1]);
  float w10 = bfu(pr1[0]), w11 = bfu(pr1[1]);
  float w20 = bfu(pr2[0]), w21 = bfu(pr2[1]);
  float f0 = bfu(pr0[2]), f1 = bfu(pr1[2]), f2 = bfu(pr2[2]);

  int aptr = 0;
  int endCur = bstart[1];

  #pragma unroll 1
  for (int xb8 = 0; xb8 < XW; xb8 += 8) {
    float pv[8];
    #pragma unroll
    for (int j = 0; j < 8; ++j) {
      const int xl = xb8 + j;
      // prefetch next patch col + next bucket end
      float g0 = 0.f, g1 = 0.f, g2 = 0.f;
      if (xl + 3 < RLEN) { g0 = bfu(pr0[xl+3]); g1 = bfu(pr1[xl+3]); g2 = bfu(pr2[xl+3]); }
      int endNxt = (xl + 2 <= XW) ? bstart[xl + 2] : 0;

      // apply this pixel's events (block-uniform control flow; v19 structure)
      while (aptr < endCur) {
        unsigned m0=0, m1=0, m2=0, m3=0, m4=0;
        if (aptr + 1 < nent) {                // rows for next event
          const unsigned* gp = W2s + nOff;
          m0 = gp[tid]; m1 = gp[256 + tid]; m2 = gp[512 + tid];
          m3 = gp[768 + tid]; m4 = gp[1024 + tid];
        }
        unsigned tOff = 0; float tc = 0.f, ta = 0.f;
        if (aptr + 2 < nent) { tOff = evOff[aptr+2]; tc = evC[aptr+2]; ta = evA[aptr+2]; }
        f32x2 ca2 = (f32x2){cc, ca};
        S[0] += (f32x2){blo(r0), blo(r0)} * ca2;
        S[1] += (f32x2){bhi(r0), bhi(r0)} * ca2;
        S[2] += (f32x2){blo(r1), blo(r1)} * ca2;
        S[3] += (f32x2){bhi(r1), bhi(r1)} * ca2;
        S[4] += (f32x2){blo(r2), blo(r2)} * ca2;
        S[5] += (f32x2){bhi(r2), bhi(r2)} * ca2;
        S[6] += (f32x2){blo(r3), blo(r3)} * ca2;
        S[7] += (f32x2){bhi(r3), bhi(r3)} * ca2;
        S[8] += (f32x2){blo(r4), blo(r4)} * ca2;
        r0=m0; r1=m1; r2=m2; r3=m3; r4=m4; cc=nc; ca=na;
        nOff=tOff; nc=tc; na=ta;
        ++aptr;
      }

      // contraction: out(o,x) contribution = sum_q patch(ic,q,x)*S[q]
      float w02 = f0, w12 = f1, w22 = f2;
      f32x2 p = (f32x2){0.f, 0.f};
      p += (f32x2){w00, w00} * S[0];
      p += (f32x2){w01, w01} * S[1];
      p += (f32x2){w02, w02} * S[2];
      p += (f32x2){w10, w10} * S[3];
      p += (f32x2){w11, w11} * S[4];
      p += (f32x2){w12, w12} * S[5];
      p += (f32x2){w20, w20} * S[6];
      p += (f32x2){w21, w21} * S[7];
      p += (f32x2){w22, w22} * S[8];
      pv[j] = fmaf((float)(x0 + xl) - fx, p[1], p[0]);   // dx lane-uniform

      w00 = w01; w01 = w02; w10 = w11; w11 = w12; w20 = w21; w21 = w22;
      f0 = g0; f1 = g1; f2 = g2;
      endCur = endNxt;
    }

    // ---- 8-value reduce-scatter butterfly over the 16 ic-lanes
    // final pv[0] at lane = sum for pixel xb8 + 4*b3 + 2*b2 + b1 (bits of c15)
    #pragma unroll
    for (int j2 = 0; j2 < 4; ++j2) {          // level m=8: 8 -> 4 values
      const bool hi = (c15 & 8) != 0;
      float keep = hi ? pv[j2 + 4] : pv[j2];
      float send = hi ? pv[j2] : pv[j2 + 4];
      pv[j2] = keep + __shfl_xor(send, 8, 64);
    }
    #pragma unroll
    for (int j2 = 0; j2 < 2; ++j2) {          // level m=4: 4 -> 2
      const bool hi = (c15 & 4) != 0;
      float keep = hi ? pv[j2 + 2] : pv[j2];
      float send = hi ? pv[j2] : pv[j2 + 2];
      pv[j2] = keep + __shfl_xor(send, 4, 64);
    }
    {                                          // level m=2: 2 -> 1
      const bool hi = (c15 & 2) != 0;
      float keep = hi ? pv[1] : pv[0];
      float send = hi ? pv[0] : pv[1];
      pv[0] = keep + __shfl_xor(send, 2, 64);
    }
    pv[0] += __shfl_xor(pv[0], 1, 64);         // level m=1: same-pixel add
    const int pxl = xb8 + 4 * ((c15 >> 3) & 1) + 2 * ((c15 >> 2) & 1) + ((c15 >> 1) & 1);
    if ((c15 & 1) == 0) shO[o * XW + pxl] = pv[0];
  }

  // ---- coalesced flush: 256 threads x 1 float4 (16B-aligned, 256B/row seg)
  __syncthreads();
  {
    int row = tid >> 4, c4 = tid & 15;
    float4 v = *(const float4*)&shO[row * XW + c4 * 4];
    *(float4*)&out[((b * CO + row) * IMGH + y) * IMGW + x0 + c4 * 4] = v;
  }
}

// ---------------------------------------------------------------------------
extern "C" void kernel_launch(void* const* d_in, const int* in_sizes, int n_in,
                              void* d_out, int out_size, void* d_ws, size_t ws_size,
                              hipStream_t stream) {
  const float* in  = (const float*)d_in[0];   // [4,16,128,128]
  const float* foa = (const float*)d_in[1];   // [4,2]
  const float* W1  = (const float*)d_in[2];   // [2,256]
  const float* b1  = (const float*)d_in[3];   // [256]
  const float* W2  = (const float*)d_in[4];   // [256,2304]
  const float* b2  = (const float*)d_in[5];   // [2304]
  float* out = (float*)d_out;
  unsigned* W2s = (unsigned*)d_ws;            // 256*5*256 dwords = 1.31 MB

  prep_w2s<<<256, 256, 0, stream>>>(W2, W2s);
  ngconv_sweep<<<1024, 256, 0, stream>>>(in, foa, W1, b1, W2s, b2, out);
}